// Round 15
// baseline (114.369 us; speedup 1.0000x reference)
//
#include <hip/hip_runtime.h>

typedef __bf16 bf16x8 __attribute__((ext_vector_type(8)));
typedef __bf16 bf16x4 __attribute__((ext_vector_type(4)));
typedef __bf16 bf16x2 __attribute__((ext_vector_type(2)));
typedef float f32x4 __attribute__((ext_vector_type(4)));
typedef unsigned short u16;
typedef unsigned int u32;

__device__ __forceinline__ f32x4 mfma16(bf16x8 a, bf16x8 b, f32x4 c) {
  return __builtin_amdgcn_mfma_f32_16x16x32_bf16(a, b, c, 0, 0, 0);
}

__device__ __forceinline__ void gload_lds16(const void* g, void* l) {
  __builtin_amdgcn_global_load_lds(
      (const __attribute__((address_space(1))) void*)g,
      (__attribute__((address_space(3))) void*)l, 16, 0, 0);
}

// CDNA4 register-pair lane swaps (VALU; both operands read+written).
__device__ __forceinline__ void swap32(u32& a, u32& b) {
  asm volatile("v_permlane32_swap_b32 %0, %1" : "+v"(a), "+v"(b));
}
__device__ __forceinline__ void swap16(u32& a, u32& b) {
  asm volatile("v_permlane16_swap_b32 %0, %1" : "+v"(a), "+v"(b));
}

__device__ __forceinline__ u32 pkbf(float a, float b) {
  union { bf16x2 h; u32 w; } u;
  u.h[0] = (__bf16)a;
  u.h[1] = (__bf16)b;
  return u.w;
}

// ---------------- prep: f32->bf16 converts (z=0..2) + weight transposes (z=3..6) -------
__global__ __launch_bounds__(256) void prep(const float4* __restrict__ qi,
                                            const float4* __restrict__ ki,
                                            const float4* __restrict__ vi,
                                            bf16x4* __restrict__ oq,
                                            bf16x4* __restrict__ ok,
                                            bf16x4* __restrict__ ov,
                                            const float* __restrict__ W0,
                                            const float* __restrict__ W1,
                                            const float* __restrict__ W2,
                                            const float* __restrict__ W3,
                                            u16* __restrict__ T0, u16* __restrict__ T1,
                                            u16* __restrict__ T2, u16* __restrict__ T3,
                                            int n4) {
  const int z = blockIdx.y;
  const int tid = threadIdx.x;
  if (z < 3) {
    int i = blockIdx.x * 256 + tid;
    if (i >= n4) return;
    const float4* in = z == 0 ? qi : z == 1 ? ki : vi;
    bf16x4* out = z == 0 ? oq : z == 1 ? ok : ov;
    float4 v = in[i];
    bf16x4 o;
    o[0] = (__bf16)v.x; o[1] = (__bf16)v.y; o[2] = (__bf16)v.z; o[3] = (__bf16)v.w;
    out[i] = o;
  } else {
    const int zz = z - 3;
    const int K = (zz == 3) ? 1024 : 512;
    const int nb = (K / 32) * 32;
    if (blockIdx.x >= nb) return;
    const float* W = zz == 0 ? W0 : zz == 1 ? W1 : zz == 2 ? W2 : W3;
    u16* Wt = zz == 0 ? T0 : zz == 1 ? T1 : zz == 2 ? T2 : T3;
    __shared__ float t[32][33];
    const int tx = tid & 31, ty = tid >> 5;
    const int n0 = (blockIdx.x & 31) * 32, k0 = (blockIdx.x >> 5) * 32;
#pragma unroll
    for (int i = 0; i < 4; ++i)
      t[ty + i * 8][tx] = W[(size_t)(k0 + ty + i * 8) * 1024 + n0 + tx];
    __syncthreads();
#pragma unroll
    for (int i = 0; i < 4; ++i)
      ((__bf16*)Wt)[(size_t)(n0 + ty + i * 8) * K + k0 + tx] = (__bf16)t[tx][ty + i * 8];
  }
}

// ---------------- 8-wave GEMM body (2x4 waves, 128x128 tile, dbuf) ----------------
// MODE 0: bf16 row-major out (scaled). MODE 2: V^T out -- Vt[(b,h,d)][kv] direct.
template <int MODE>
__device__ __forceinline__ void gemm8_body(const u16* __restrict__ A,
                                           const u16* __restrict__ Bt,
                                           const float* __restrict__ bias,
                                           u16* __restrict__ Cout,
                                           int N, int K, float scl) {
  __shared__ __align__(16) u16 lA[2][128 * 64];
  __shared__ __align__(16) u16 lB[2][128 * 64];
  const int tid = threadIdx.x;
  const int w = tid >> 6, l = tid & 63;
  const int li = l & 15, lg = l >> 4;
  const int wm = w & 1, wn = w >> 1;  // wn 0..3
  const int bm = blockIdx.x * 128, bn = blockIdx.y * 128;

  f32x4 acc[4][2] = {};
  const int nk = K >> 6;

  auto stage = [&](int kt, int bufi) {
    const int k0 = kt << 6;
#pragma unroll
    for (int i = 0; i < 2; ++i) {
      const int c0 = (i * 8 + w) * 64;
      const int f = c0 + l;
      const int r = f >> 3, cs = (f & 7) ^ (r & 7);
      gload_lds16(A + (size_t)(bm + r) * K + k0 + cs * 8, &lA[bufi][c0 * 8]);
      gload_lds16(Bt + (size_t)(bn + r) * K + k0 + cs * 8, &lB[bufi][c0 * 8]);
    }
  };

  int cur = 0;
  stage(0, 0);
  __syncthreads();

  for (int kt = 0; kt < nk; ++kt) {
    if (kt + 1 < nk) stage(kt + 1, cur ^ 1);
    bf16x8 af[4][2], bfr[2][2];
#pragma unroll
    for (int m = 0; m < 4; ++m) {
      const int row = wm * 64 + m * 16 + li;
#pragma unroll
      for (int kk = 0; kk < 2; ++kk) {
        const int kc = (lg + kk * 4) ^ (row & 7);
        af[m][kk] = *(const bf16x8*)&lA[cur][row * 64 + kc * 8];
      }
    }
#pragma unroll
    for (int n = 0; n < 2; ++n) {
      const int row = wn * 32 + n * 16 + li;
#pragma unroll
      for (int kk = 0; kk < 2; ++kk) {
        const int kc = (lg + kk * 4) ^ (row & 7);
        bfr[n][kk] = *(const bf16x8*)&lB[cur][row * 64 + kc * 8];
      }
    }
#pragma unroll
    for (int m = 0; m < 4; ++m)
#pragma unroll
      for (int n = 0; n < 2; ++n) {
        acc[m][n] = mfma16(af[m][0], bfr[n][0], acc[m][n]);
        acc[m][n] = mfma16(af[m][1], bfr[n][1], acc[m][n]);
      }
    __syncthreads();
    cur ^= 1;
  }

#pragma unroll
  for (int m = 0; m < 4; ++m) {
    const int row0 = bm + wm * 64 + m * 16 + lg * 4;
#pragma unroll
    for (int n = 0; n < 2; ++n) {
      const int col = bn + wn * 32 + n * 16 + li;
      const float bv = bias[col];
      if (MODE == 2) {
        const int bq = row0 >> 11, kv = row0 & 2047;
        bf16x4 pk;
#pragma unroll
        for (int r = 0; r < 4; ++r) pk[r] = (__bf16)((acc[m][n][r] + bv) * scl);
        *(bf16x4*)&Cout[((size_t)(bq * 1024 + col)) * 2048 + kv] = pk;
      } else {
#pragma unroll
        for (int r = 0; r < 4; ++r)
          ((__bf16*)Cout)[(size_t)(row0 + r) * N + col] = (__bf16)((acc[m][n][r] + bv) * scl);
      }
    }
  }
}

// QKV projections in one launch (8 waves): z selects the matmul; z==2 writes V^T.
__global__ __launch_bounds__(512) void gemm_qkv8(const u16* __restrict__ xq,
                                                 const u16* __restrict__ xk,
                                                 const u16* __restrict__ xv,
                                                 const u16* __restrict__ wqt,
                                                 const u16* __restrict__ wkt,
                                                 const u16* __restrict__ wvt,
                                                 const float* __restrict__ bq,
                                                 const float* __restrict__ bk,
                                                 const float* __restrict__ bv,
                                                 u16* __restrict__ Qb, u16* __restrict__ Kb,
                                                 u16* __restrict__ Vt, float qscale) {
  const int z = blockIdx.z;
  if (z == 0) {
    gemm8_body<0>(xq, wqt, bq, Qb, 1024, 512, qscale);
  } else if (z == 1) {
    gemm8_body<0>(xk, wkt, bk, Kb, 1024, 512, 1.0f);
  } else {
    gemm8_body<2>(xv, wvt, bv, Vt, 1024, 512, 1.0f);
  }
}

// ---------------- output GEMM with FUSED COMBINE (8 waves, dbuf) ----------------
// A = (Opart0 + Opart1) * (1/(l0+l1)) computed in registers during staging
// (T14 issue-early/write-late: loads issue before the MFMA block, ds_write after).
// Per K-tile kt the A-chunk's head is exactly kt (k0 = 64*kt), so the scale is
// one scalar per (row, kt). B stays global_load_lds.
__global__ __launch_bounds__(512) void gemm_oc(const u16* __restrict__ Op0,
                                               const u16* __restrict__ Op1,
                                               const float* __restrict__ Lp0,
                                               const float* __restrict__ Lp1,
                                               const u16* __restrict__ Bt,
                                               const float* __restrict__ bias,
                                               u16* __restrict__ C) {
  constexpr int N = 1024, K = 1024;
  __shared__ __align__(16) u16 lA[2][128 * 64];
  __shared__ __align__(16) u16 lB[2][128 * 64];
  const int tid = threadIdx.x;
  const int w = tid >> 6, l = tid & 63;
  const int li = l & 15, lg = l >> 4;
  const int wm = w & 1, wn = w >> 1;
  const int bm = blockIdx.x * 128, bn = blockIdx.y * 128;

  f32x4 acc[4][2] = {};
  const int nk = K >> 6;  // 16

  bf16x8 a0[2], a1[2];
  float inv[2];

  auto loadA = [&](int kt) {
    const int k0 = kt << 6;
#pragma unroll
    for (int i = 0; i < 2; ++i) {
      const int c0 = (i * 8 + w) * 64;
      const int f = c0 + l;
      const int r = f >> 3, cs = (f & 7) ^ (r & 7);
      const int row = bm + r;
      a0[i] = *(const bf16x8*)&Op0[(size_t)row * 1024 + k0 + cs * 8];
      a1[i] = *(const bf16x8*)&Op1[(size_t)row * 1024 + k0 + cs * 8];
      inv[i] = 1.f / (Lp0[row * 16 + kt] + Lp1[row * 16 + kt]);
    }
  };
  auto writeA = [&](int bufi) {
#pragma unroll
    for (int i = 0; i < 2; ++i) {
      const int c0 = (i * 8 + w) * 64;
      bf16x8 o;
#pragma unroll
      for (int j = 0; j < 8; ++j)
        o[j] = (__bf16)(((float)a0[i][j] + (float)a1[i][j]) * inv[i]);
      *(bf16x8*)&lA[bufi][c0 * 8 + l * 8] = o;
    }
  };
  auto stageB = [&](int kt, int bufi) {
    const int k0 = kt << 6;
#pragma unroll
    for (int i = 0; i < 2; ++i) {
      const int c0 = (i * 8 + w) * 64;
      const int f = c0 + l;
      const int r = f >> 3, cs = (f & 7) ^ (r & 7);
      gload_lds16(Bt + (size_t)(bn + r) * K + k0 + cs * 8, &lB[bufi][c0 * 8]);
    }
  };

  int cur = 0;
  loadA(0);
  stageB(0, 0);
  writeA(0);
  __syncthreads();

  for (int kt = 0; kt < nk; ++kt) {
    if (kt + 1 < nk) {
      loadA(kt + 1);            // issue early
      stageB(kt + 1, cur ^ 1);  // async -> lB[cur^1]
    }
    bf16x8 af[4][2], bfr[2][2];
#pragma unroll
    for (int m = 0; m < 4; ++m) {
      const int row = wm * 64 + m * 16 + li;
#pragma unroll
      for (int kk = 0; kk < 2; ++kk) {
        const int kc = (lg + kk * 4) ^ (row & 7);
        af[m][kk] = *(const bf16x8*)&lA[cur][row * 64 + kc * 8];
      }
    }
#pragma unroll
    for (int n = 0; n < 2; ++n) {
      const int row = wn * 32 + n * 16 + li;
#pragma unroll
      for (int kk = 0; kk < 2; ++kk) {
        const int kc = (lg + kk * 4) ^ (row & 7);
        bfr[n][kk] = *(const bf16x8*)&lB[cur][row * 64 + kc * 8];
      }
    }
#pragma unroll
    for (int m = 0; m < 4; ++m)
#pragma unroll
      for (int n = 0; n < 2; ++n) {
        acc[m][n] = mfma16(af[m][0], bfr[n][0], acc[m][n]);
        acc[m][n] = mfma16(af[m][1], bfr[n][1], acc[m][n]);
      }
    if (kt + 1 < nk) writeA(cur ^ 1);  // vmcnt wait lands here, after MFMA
    __syncthreads();
    cur ^= 1;
  }

#pragma unroll
  for (int m = 0; m < 4; ++m) {
    const int row0 = bm + wm * 64 + m * 16 + lg * 4;
#pragma unroll
    for (int n = 0; n < 2; ++n) {
      const int col = bn + wn * 32 + n * 16 + li;
      const float bv = bias[col];
#pragma unroll
      for (int r = 0; r < 4; ++r)
        ((__bf16*)C)[(size_t)(row0 + r) * N + col] = (__bf16)(acc[m][n][r] + bv);
    }
  }
}

// ---------------- flash attention fwd, D=64, QBLK=256 (8 waves x 2 q-streams) ----------
// + KV-SPLIT x2 (no-max softmax linear in kv); partials merged in gemm_oc.
// + 2-tile unroll (4-buffer ring). P never touches LDS (permlane exchange).
__global__ __launch_bounds__(512, 4) void attn64(const u16* __restrict__ Qb,
                                                 const u16* __restrict__ Kb,
                                                 const u16* __restrict__ Vt,
                                                 u16* __restrict__ Opart,
                                                 float* __restrict__ Lpart,
                                                 int N1, int N2) {
  const int tid = threadIdx.x;
  const int w = tid >> 6, l = tid & 63;
  const int li = l & 15, lg = l >> 4;

  // XCD remap: grid (8,16,4) = 512 blocks; XCD = flat & 7.
  const int flat = blockIdx.x + 8 * (blockIdx.y + 16 * blockIdx.z);
  const int xcd = flat & 7, idx = flat >> 3;   // 0..63
  const int qb = idx & 7, rest = idx >> 3;     // rest 0..7
  const int h = 2 * xcd + (rest & 1);
  const int b = (rest >> 1) & 1;
  const int kvh = rest >> 2;
  const int q0 = qb * 256;

  __shared__ __align__(16) u16 lK[4][64 * 64];   // [kv][d], chunk-swizzled (32 KB)
  __shared__ __align__(16) u16 lV[4][64 * 64];   // [d][kv], chunk-swizzled (32 KB)

  bf16x8 qa[2][2];
#pragma unroll
  for (int s = 0; s < 2; ++s) {
    const size_t qoff = (size_t)(b * N1 + q0 + s * 128 + w * 16 + li) * 1024 + h * 64;
    qa[s][0] = *(const bf16x8*)&Qb[qoff + lg * 8];
    qa[s][1] = *(const bf16x8*)&Qb[qoff + 32 + lg * 8];
  }

  const u16* Kbase = Kb + (size_t)b * N2 * 1024 + h * 64;
  const u16* Vbase = Vt + (size_t)((b * 16 + h) * 64) * N2;

  const int sr = tid >> 3;
  const int sc = (tid & 7) ^ (sr & 7);

  f32x4 o[2][4] = {};
  float lsum0 = 0.f, lsum1 = 0.f;
  const int ca = lg ^ (li & 7), cb = (lg + 4) ^ (li & 7);

  auto stageK = [&](int t, int bufi) {
    gload_lds16(Kbase + (size_t)(t * 64 + sr) * 1024 + sc * 8, &lK[bufi][w * 512]);
  };
  auto stageV = [&](int t, int bufi) {
    gload_lds16(Vbase + (size_t)sr * N2 + t * 64 + sc * 8, &lV[bufi][w * 512]);
  };

  auto tile_body = [&](const u16* K_, const u16* V_) {
    float st0 = 0.f, st1 = 0.f;
    u32 u0[4][2], u1[4][2];
    __builtin_amdgcn_s_setprio(1);
#pragma unroll
    for (int n = 0; n < 4; ++n) {
      const int row = n * 16 + li;
      bf16x8 k0 = *(const bf16x8*)&K_[row * 64 + ca * 8];
      bf16x8 k1 = *(const bf16x8*)&K_[row * 64 + cb * 8];
      f32x4 a = {}, a2 = {};
      a = mfma16(k0, qa[0][0], a);
      a = mfma16(k1, qa[0][1], a);
      a2 = mfma16(k0, qa[1][0], a2);
      a2 = mfma16(k1, qa[1][1], a2);
      float p0 = __builtin_amdgcn_exp2f(a[0]);
      float p1 = __builtin_amdgcn_exp2f(a[1]);
      float p2 = __builtin_amdgcn_exp2f(a[2]);
      float p3 = __builtin_amdgcn_exp2f(a[3]);
      st0 += (p0 + p1) + (p2 + p3);
      u0[n][0] = pkbf(p0, p1);
      u0[n][1] = pkbf(p2, p3);
      float r0 = __builtin_amdgcn_exp2f(a2[0]);
      float r1 = __builtin_amdgcn_exp2f(a2[1]);
      float r2 = __builtin_amdgcn_exp2f(a2[2]);
      float r3 = __builtin_amdgcn_exp2f(a2[3]);
      st1 += (r0 + r1) + (r2 + r3);
      u1[n][0] = pkbf(r0, r1);
      u1[n][1] = pkbf(r2, r3);
    }
    __builtin_amdgcn_s_setprio(0);
    lsum0 += st0;
    lsum1 += st1;

    // register exchange: (b4,b5,n0,n1) -> (b5,n0,b4,n1)
#pragma unroll
    for (int c = 0; c < 2; ++c) {
      swap32(u0[0][c], u0[1][c]); swap32(u0[2][c], u0[3][c]);
      swap32(u1[0][c], u1[1][c]); swap32(u1[2][c], u1[3][c]);
    }
#pragma unroll
    for (int c = 0; c < 2; ++c) {
      swap16(u0[0][c], u0[1][c]); swap16(u0[2][c], u0[3][c]);
      swap16(u1[0][c], u1[1][c]); swap16(u1[2][c], u1[3][c]);
    }

    __builtin_amdgcn_s_setprio(1);
#pragma unroll
    for (int ks = 0; ks < 2; ++ks) {
      union { u32 w4[4]; bf16x8 v; } f0, f1;
      f0.w4[0] = u0[2 * ks][0]; f0.w4[1] = u0[2 * ks][1];
      f0.w4[2] = u0[2 * ks + 1][0]; f0.w4[3] = u0[2 * ks + 1][1];
      f1.w4[0] = u1[2 * ks][0]; f1.w4[1] = u1[2 * ks][1];
      f1.w4[2] = u1[2 * ks + 1][0]; f1.w4[3] = u1[2 * ks + 1][1];
#pragma unroll
      for (int dt = 0; dt < 4; ++dt) {
        const int row = dt * 16 + li;
        const int c = (lg + ks * 4) ^ (li & 7);
        const bf16x8 vf = *(const bf16x8*)&V_[row * 64 + c * 8];
        o[0][dt] = mfma16(vf, f0.v, o[0][dt]);
        o[1][dt] = mfma16(vf, f1.v, o[1][dt]);
      }
    }
    __builtin_amdgcn_s_setprio(0);
  };

  const int t0 = kvh * 16;

  stageK(t0, 0); stageV(t0, 0);
  stageK(t0 + 1, 1); stageV(t0 + 1, 1);
  __syncthreads();

  for (int tt = 0; tt < 16; tt += 2) {
    const int t = t0 + tt;
    if (tt + 2 < 16) { stageK(t + 2, (tt + 2) & 3); stageV(t + 2, (tt + 2) & 3); }
    if (tt + 3 < 16) { stageK(t + 3, (tt + 3) & 3); stageV(t + 3, (tt + 3) & 3); }
    tile_body(lK[tt & 3], lV[tt & 3]);
    tile_body(lK[(tt + 1) & 3], lV[(tt + 1) & 3]);
    __syncthreads();
  }

  lsum0 += __shfl_xor(lsum0, 16, 64);
  lsum0 += __shfl_xor(lsum0, 32, 64);
  lsum1 += __shfl_xor(lsum1, 16, 64);
  lsum1 += __shfl_xor(lsum1, 32, 64);

  u16* Op = Opart + (size_t)kvh * 4096 * 1024;
#pragma unroll
  for (int s = 0; s < 2; ++s) {
    const int qrow = b * N1 + q0 + s * 128 + w * 16 + li;
    const size_t orow = (size_t)qrow * 1024 + h * 64;
#pragma unroll
    for (int dt = 0; dt < 4; ++dt) {
      bf16x4 pk;
#pragma unroll
      for (int r = 0; r < 4; ++r) pk[r] = (__bf16)o[s][dt][r];
      *(bf16x4*)&Op[orow + dt * 16 + lg * 4] = pk;
    }
    if (lg == 0)
      Lpart[(size_t)kvh * 4096 * 16 + (size_t)qrow * 16 + h] = (s == 0 ? lsum0 : lsum1);
  }
}

// ---------------- LayerNorm over 1024 cols (bf16 in, f32 out) ----------------
__global__ __launch_bounds__(256) void lnorm(const u16* __restrict__ X,
                                             const float* __restrict__ gamma,
                                             const float* __restrict__ beta,
                                             float* __restrict__ out) {
  const int row = blockIdx.x;
  const int tid = threadIdx.x;
  const bf16x4 xv = ((const bf16x4*)(X + (size_t)row * 1024))[tid];
  float4 v;
  v.x = (float)xv[0]; v.y = (float)xv[1]; v.z = (float)xv[2]; v.w = (float)xv[3];
  float s = v.x + v.y + v.z + v.w;
  float sq = v.x * v.x + v.y * v.y + v.z * v.z + v.w * v.w;
#pragma unroll
  for (int d = 1; d < 64; d <<= 1) {
    s += __shfl_xor(s, d, 64);
    sq += __shfl_xor(sq, d, 64);
  }
  __shared__ float red[8];
  const int w = tid >> 6, l = tid & 63;
  if (l == 0) { red[w] = s; red[4 + w] = sq; }
  __syncthreads();
  s = red[0] + red[1] + red[2] + red[3];
  sq = red[4] + red[5] + red[6] + red[7];
  const float mu = s * (1.f / 1024.f);
  const float var = sq * (1.f / 1024.f) - mu * mu;
  const float rstd = rsqrtf(var + 1e-5f);
  const float4 g = ((const float4*)gamma)[tid];
  const float4 bb = ((const float4*)beta)[tid];
  float4 o;
  o.x = (v.x - mu) * rstd * g.x + bb.x;
  o.y = (v.y - mu) * rstd * g.y + bb.y;
  o.z = (v.z - mu) * rstd * g.z + bb.z;
  o.w = (v.w - mu) * rstd * g.w + bb.w;
  ((float4*)(out + (size_t)row * 1024))[tid] = o;
}

extern "C" void kernel_launch(void* const* d_in, const int* in_sizes, int n_in,
                              void* d_out, int out_size, void* d_ws, size_t ws_size,
                              hipStream_t stream) {
  const float* query = (const float*)d_in[0];
  const float* key_ = (const float*)d_in[1];
  const float* value = (const float*)d_in[2];
  const float* Wq = (const float*)d_in[3];
  const float* bq = (const float*)d_in[4];
  const float* Wk = (const float*)d_in[5];
  const float* bk = (const float*)d_in[6];
  const float* Wv = (const float*)d_in[7];
  const float* bv = (const float*)d_in[8];
  const float* Wo = (const float*)d_in[9];
  const float* bo = (const float*)d_in[10];
  const float* gamma = (const float*)d_in[11];
  const float* beta = (const float*)d_in[12];

  constexpr int B = 2, N1 = 2048, N2 = 2048, E = 1024, QKD = 512;
  constexpr int M = B * N1;  // 4096
  const float QSCALE = 0.125f * 1.4426950408889634f;  // 1/sqrt(64) * log2(e)

  char* p = (char*)d_ws;
  auto alloc = [&](size_t bytes) {
    char* r = p;
    p += (bytes + 255) & ~(size_t)255;
    return r;
  };
  u16* xq = (u16*)alloc((size_t)M * QKD * 2);
  u16* xk = (u16*)alloc((size_t)M * QKD * 2);
  u16* xv = (u16*)alloc((size_t)M * QKD * 2);
  u16* wqt = (u16*)alloc((size_t)E * QKD * 2);
  u16* wkt = (u16*)alloc((size_t)E * QKD * 2);
  u16* wvt = (u16*)alloc((size_t)E * QKD * 2);
  u16* wot = (u16*)alloc((size_t)E * E * 2);
  u16* Qb = (u16*)alloc((size_t)M * E * 2);
  u16* Kb = (u16*)alloc((size_t)M * E * 2);
  u16* Vt = (u16*)alloc((size_t)M * E * 2);
  u16* ao2 = (u16*)alloc((size_t)M * E * 2);
  u16* Opart = (u16*)alloc((size_t)2 * M * E * 2);
  float* Lpart = (float*)alloc((size_t)2 * M * 16 * 4);

  const int n4 = M * QKD / 4;
  prep<<<dim3((n4 + 255) / 256, 7), 256, 0, stream>>>(
      (const float4*)query, (const float4*)key_, (const float4*)value,
      (bf16x4*)xq, (bf16x4*)xk, (bf16x4*)xv,
      Wq, Wk, Wv, Wo, wqt, wkt, wvt, wot, n4);

  gemm_qkv8<<<dim3(M / 128, E / 128, 3), 512, 0, stream>>>(
      xq, xk, xv, wqt, wkt, wvt, bq, bk, bv, Qb, Kb, Vt, QSCALE);

  attn64<<<dim3(8, 16, 4), 512, 0, stream>>>(Qb, Kb, Vt, Opart, Lpart, N1, N2);

  gemm_oc<<<dim3(M / 128, E / 128), 512, 0, stream>>>(
      Opart, Opart + (size_t)M * E, Lpart, Lpart + (size_t)M * 16,
      wot, bo, ao2);

  lnorm<<<M, 256, 0, stream>>>(ao2, gamma, beta, (float*)d_out);
}

// Round 16
// 100.800 us; speedup vs baseline: 1.1346x; 1.1346x over previous
//
#include <hip/hip_runtime.h>

typedef __bf16 bf16x8 __attribute__((ext_vector_type(8)));
typedef __bf16 bf16x4 __attribute__((ext_vector_type(4)));
typedef __bf16 bf16x2 __attribute__((ext_vector_type(2)));
typedef float f32x4 __attribute__((ext_vector_type(4)));
typedef unsigned short u16;
typedef unsigned int u32;

__device__ __forceinline__ f32x4 mfma16(bf16x8 a, bf16x8 b, f32x4 c) {
  return __builtin_amdgcn_mfma_f32_16x16x32_bf16(a, b, c, 0, 0, 0);
}

__device__ __forceinline__ void gload_lds16(const void* g, void* l) {
  __builtin_amdgcn_global_load_lds(
      (const __attribute__((address_space(1))) void*)g,
      (__attribute__((address_space(3))) void*)l, 16, 0, 0);
}

// CDNA4 register-pair lane swaps (VALU; both operands read+written).
__device__ __forceinline__ void swap32(u32& a, u32& b) {
  asm volatile("v_permlane32_swap_b32 %0, %1" : "+v"(a), "+v"(b));
}
__device__ __forceinline__ void swap16(u32& a, u32& b) {
  asm volatile("v_permlane16_swap_b32 %0, %1" : "+v"(a), "+v"(b));
}

__device__ __forceinline__ u32 pkbf(float a, float b) {
  union { bf16x2 h; u32 w; } u;
  u.h[0] = (__bf16)a;
  u.h[1] = (__bf16)b;
  return u.w;
}

// ---------------- prep: f32->bf16 converts (z=0..2) + weight transposes (z=3..6) -------
__global__ __launch_bounds__(256) void prep(const float4* __restrict__ qi,
                                            const float4* __restrict__ ki,
                                            const float4* __restrict__ vi,
                                            bf16x4* __restrict__ oq,
                                            bf16x4* __restrict__ ok,
                                            bf16x4* __restrict__ ov,
                                            const float* __restrict__ W0,
                                            const float* __restrict__ W1,
                                            const float* __restrict__ W2,
                                            const float* __restrict__ W3,
                                            u16* __restrict__ T0, u16* __restrict__ T1,
                                            u16* __restrict__ T2, u16* __restrict__ T3,
                                            int n4) {
  const int z = blockIdx.y;
  const int tid = threadIdx.x;
  if (z < 3) {
    int i = blockIdx.x * 256 + tid;
    if (i >= n4) return;
    const float4* in = z == 0 ? qi : z == 1 ? ki : vi;
    bf16x4* out = z == 0 ? oq : z == 1 ? ok : ov;
    float4 v = in[i];
    bf16x4 o;
    o[0] = (__bf16)v.x; o[1] = (__bf16)v.y; o[2] = (__bf16)v.z; o[3] = (__bf16)v.w;
    out[i] = o;
  } else {
    const int zz = z - 3;
    const int K = (zz == 3) ? 1024 : 512;
    const int nb = (K / 32) * 32;
    if (blockIdx.x >= nb) return;
    const float* W = zz == 0 ? W0 : zz == 1 ? W1 : zz == 2 ? W2 : W3;
    u16* Wt = zz == 0 ? T0 : zz == 1 ? T1 : zz == 2 ? T2 : T3;
    __shared__ float t[32][33];
    const int tx = tid & 31, ty = tid >> 5;
    const int n0 = (blockIdx.x & 31) * 32, k0 = (blockIdx.x >> 5) * 32;
#pragma unroll
    for (int i = 0; i < 4; ++i)
      t[ty + i * 8][tx] = W[(size_t)(k0 + ty + i * 8) * 1024 + n0 + tx];
    __syncthreads();
#pragma unroll
    for (int i = 0; i < 4; ++i)
      ((__bf16*)Wt)[(size_t)(n0 + ty + i * 8) * K + k0 + tx] = (__bf16)t[tx][ty + i * 8];
  }
}

// ---------------- 8-wave NON-DBUF GEMM body (2x4 waves, 128x128 tile, 32KB LDS) --------
// 3 blocks/CU for the 768-block QKV grid -> 24 waves/CU, no scheduling tail.
// MODE 0: bf16 row-major out (scaled). MODE 2: V^T out -- Vt[(b,h,d)][kv] direct.
template <int MODE>
__device__ __forceinline__ void gemm8nd_body(const u16* __restrict__ A,
                                             const u16* __restrict__ Bt,
                                             const float* __restrict__ bias,
                                             u16* __restrict__ Cout,
                                             int N, int K, float scl) {
  __shared__ __align__(16) u16 lA[128 * 64];
  __shared__ __align__(16) u16 lB[128 * 64];
  const int tid = threadIdx.x;
  const int w = tid >> 6, l = tid & 63;
  const int li = l & 15, lg = l >> 4;
  const int wm = w & 1, wn = w >> 1;  // wn 0..3
  const int bm = blockIdx.x * 128, bn = blockIdx.y * 128;

  f32x4 acc[4][2] = {};
  const int nk = K >> 6;

  for (int kt = 0; kt < nk; ++kt) {
    const int k0 = kt << 6;
#pragma unroll
    for (int i = 0; i < 2; ++i) {
      const int c0 = (i * 8 + w) * 64;
      const int f = c0 + l;
      const int r = f >> 3, cs = (f & 7) ^ (r & 7);
      gload_lds16(A + (size_t)(bm + r) * K + k0 + cs * 8, &lA[c0 * 8]);
      gload_lds16(Bt + (size_t)(bn + r) * K + k0 + cs * 8, &lB[c0 * 8]);
    }
    __syncthreads();
    bf16x8 af[4][2], bfr[2][2];
#pragma unroll
    for (int m = 0; m < 4; ++m) {
      const int row = wm * 64 + m * 16 + li;
#pragma unroll
      for (int kk = 0; kk < 2; ++kk) {
        const int kc = (lg + kk * 4) ^ (row & 7);
        af[m][kk] = *(const bf16x8*)&lA[row * 64 + kc * 8];
      }
    }
#pragma unroll
    for (int n = 0; n < 2; ++n) {
      const int row = wn * 32 + n * 16 + li;
#pragma unroll
      for (int kk = 0; kk < 2; ++kk) {
        const int kc = (lg + kk * 4) ^ (row & 7);
        bfr[n][kk] = *(const bf16x8*)&lB[row * 64 + kc * 8];
      }
    }
#pragma unroll
    for (int m = 0; m < 4; ++m)
#pragma unroll
      for (int n = 0; n < 2; ++n) {
        acc[m][n] = mfma16(af[m][0], bfr[n][0], acc[m][n]);
        acc[m][n] = mfma16(af[m][1], bfr[n][1], acc[m][n]);
      }
    __syncthreads();
  }

#pragma unroll
  for (int m = 0; m < 4; ++m) {
    const int row0 = bm + wm * 64 + m * 16 + lg * 4;
#pragma unroll
    for (int n = 0; n < 2; ++n) {
      const int col = bn + wn * 32 + n * 16 + li;
      const float bv = bias[col];
      if (MODE == 2) {
        const int bq = row0 >> 11, kv = row0 & 2047;
        bf16x4 pk;
#pragma unroll
        for (int r = 0; r < 4; ++r) pk[r] = (__bf16)((acc[m][n][r] + bv) * scl);
        *(bf16x4*)&Cout[((size_t)(bq * 1024 + col)) * 2048 + kv] = pk;
      } else {
#pragma unroll
        for (int r = 0; r < 4; ++r)
          ((__bf16*)Cout)[(size_t)(row0 + r) * N + col] = (__bf16)((acc[m][n][r] + bv) * scl);
      }
    }
  }
}

// QKV projections in one launch (8 waves, non-dbuf): z selects; z==2 writes V^T.
__global__ __launch_bounds__(512) void gemm_qkv8(const u16* __restrict__ xq,
                                                 const u16* __restrict__ xk,
                                                 const u16* __restrict__ xv,
                                                 const u16* __restrict__ wqt,
                                                 const u16* __restrict__ wkt,
                                                 const u16* __restrict__ wvt,
                                                 const float* __restrict__ bq,
                                                 const float* __restrict__ bk,
                                                 const float* __restrict__ bv,
                                                 u16* __restrict__ Qb, u16* __restrict__ Kb,
                                                 u16* __restrict__ Vt, float qscale) {
  const int z = blockIdx.z;
  if (z == 0) {
    gemm8nd_body<0>(xq, wqt, bq, Qb, 1024, 512, qscale);
  } else if (z == 1) {
    gemm8nd_body<0>(xk, wkt, bk, Kb, 1024, 512, 1.0f);
  } else {
    gemm8nd_body<2>(xv, wvt, bv, Vt, 1024, 512, 1.0f);
  }
}

// ---------------- output GEMM: 8 waves (2x4), 128x128 tile, dbuf (R14-proven) ----------
__global__ __launch_bounds__(512) void gemm_o8(const u16* __restrict__ A,
                                               const u16* __restrict__ Bt,
                                               const float* __restrict__ bias,
                                               u16* __restrict__ C) {
  constexpr int N = 1024, K = 1024;
  __shared__ __align__(16) u16 lA[2][128 * 64];
  __shared__ __align__(16) u16 lB[2][128 * 64];
  const int tid = threadIdx.x;
  const int w = tid >> 6, l = tid & 63;
  const int li = l & 15, lg = l >> 4;
  const int wm = w & 1, wn = w >> 1;
  const int bm = blockIdx.x * 128, bn = blockIdx.y * 128;

  f32x4 acc[4][2] = {};
  const int nk = K >> 6;  // 16

  auto stage = [&](int kt, int bufi) {
    const int k0 = kt << 6;
#pragma unroll
    for (int i = 0; i < 2; ++i) {
      const int c0 = (i * 8 + w) * 64;
      const int f = c0 + l;
      const int r = f >> 3, cs = (f & 7) ^ (r & 7);
      gload_lds16(A + (size_t)(bm + r) * K + k0 + cs * 8, &lA[bufi][c0 * 8]);
      gload_lds16(Bt + (size_t)(bn + r) * K + k0 + cs * 8, &lB[bufi][c0 * 8]);
    }
  };

  int cur = 0;
  stage(0, 0);
  __syncthreads();

  for (int kt = 0; kt < nk; ++kt) {
    if (kt + 1 < nk) stage(kt + 1, cur ^ 1);
    bf16x8 af[4][2], bfr[2][2];
#pragma unroll
    for (int m = 0; m < 4; ++m) {
      const int row = wm * 64 + m * 16 + li;
#pragma unroll
      for (int kk = 0; kk < 2; ++kk) {
        const int kc = (lg + kk * 4) ^ (row & 7);
        af[m][kk] = *(const bf16x8*)&lA[cur][row * 64 + kc * 8];
      }
    }
#pragma unroll
    for (int n = 0; n < 2; ++n) {
      const int row = wn * 32 + n * 16 + li;
#pragma unroll
      for (int kk = 0; kk < 2; ++kk) {
        const int kc = (lg + kk * 4) ^ (row & 7);
        bfr[n][kk] = *(const bf16x8*)&lB[cur][row * 64 + kc * 8];
      }
    }
#pragma unroll
    for (int m = 0; m < 4; ++m)
#pragma unroll
      for (int n = 0; n < 2; ++n) {
        acc[m][n] = mfma16(af[m][0], bfr[n][0], acc[m][n]);
        acc[m][n] = mfma16(af[m][1], bfr[n][1], acc[m][n]);
      }
    __syncthreads();
    cur ^= 1;
  }

#pragma unroll
  for (int m = 0; m < 4; ++m) {
    const int row0 = bm + wm * 64 + m * 16 + lg * 4;
#pragma unroll
    for (int n = 0; n < 2; ++n) {
      const int col = bn + wn * 32 + n * 16 + li;
      const float bv = bias[col];
#pragma unroll
      for (int r = 0; r < 4; ++r)
        ((__bf16*)C)[(size_t)(row0 + r) * N + col] = (__bf16)(acc[m][n][r] + bv);
    }
  }
}

// ---------------- flash attention fwd, D=64, QBLK=256 (8 waves x 2 q-streams) ----------
// + KV-SPLIT x2 (no-max softmax linear in kv) with combine() merge.
// + 2-tile unroll (4-buffer ring). P never touches LDS (permlane exchange).
__global__ __launch_bounds__(512, 4) void attn64(const u16* __restrict__ Qb,
                                                 const u16* __restrict__ Kb,
                                                 const u16* __restrict__ Vt,
                                                 u16* __restrict__ Opart,
                                                 float* __restrict__ Lpart,
                                                 int N1, int N2) {
  const int tid = threadIdx.x;
  const int w = tid >> 6, l = tid & 63;
  const int li = l & 15, lg = l >> 4;

  // XCD remap: grid (8,16,4) = 512 blocks; XCD = flat & 7.
  const int flat = blockIdx.x + 8 * (blockIdx.y + 16 * blockIdx.z);
  const int xcd = flat & 7, idx = flat >> 3;   // 0..63
  const int qb = idx & 7, rest = idx >> 3;     // rest 0..7
  const int h = 2 * xcd + (rest & 1);
  const int b = (rest >> 1) & 1;
  const int kvh = rest >> 2;
  const int q0 = qb * 256;

  __shared__ __align__(16) u16 lK[4][64 * 64];   // [kv][d], chunk-swizzled (32 KB)
  __shared__ __align__(16) u16 lV[4][64 * 64];   // [d][kv], chunk-swizzled (32 KB)

  bf16x8 qa[2][2];
#pragma unroll
  for (int s = 0; s < 2; ++s) {
    const size_t qoff = (size_t)(b * N1 + q0 + s * 128 + w * 16 + li) * 1024 + h * 64;
    qa[s][0] = *(const bf16x8*)&Qb[qoff + lg * 8];
    qa[s][1] = *(const bf16x8*)&Qb[qoff + 32 + lg * 8];
  }

  const u16* Kbase = Kb + (size_t)b * N2 * 1024 + h * 64;
  const u16* Vbase = Vt + (size_t)((b * 16 + h) * 64) * N2;

  const int sr = tid >> 3;
  const int sc = (tid & 7) ^ (sr & 7);

  f32x4 o[2][4] = {};
  float lsum0 = 0.f, lsum1 = 0.f;
  const int ca = lg ^ (li & 7), cb = (lg + 4) ^ (li & 7);

  auto stageK = [&](int t, int bufi) {
    gload_lds16(Kbase + (size_t)(t * 64 + sr) * 1024 + sc * 8, &lK[bufi][w * 512]);
  };
  auto stageV = [&](int t, int bufi) {
    gload_lds16(Vbase + (size_t)sr * N2 + t * 64 + sc * 8, &lV[bufi][w * 512]);
  };

  auto tile_body = [&](const u16* K_, const u16* V_) {
    float st0 = 0.f, st1 = 0.f;
    u32 u0[4][2], u1[4][2];
    __builtin_amdgcn_s_setprio(1);
#pragma unroll
    for (int n = 0; n < 4; ++n) {
      const int row = n * 16 + li;
      bf16x8 k0 = *(const bf16x8*)&K_[row * 64 + ca * 8];
      bf16x8 k1 = *(const bf16x8*)&K_[row * 64 + cb * 8];
      f32x4 a = {}, a2 = {};
      a = mfma16(k0, qa[0][0], a);
      a = mfma16(k1, qa[0][1], a);
      a2 = mfma16(k0, qa[1][0], a2);
      a2 = mfma16(k1, qa[1][1], a2);
      float p0 = __builtin_amdgcn_exp2f(a[0]);
      float p1 = __builtin_amdgcn_exp2f(a[1]);
      float p2 = __builtin_amdgcn_exp2f(a[2]);
      float p3 = __builtin_amdgcn_exp2f(a[3]);
      st0 += (p0 + p1) + (p2 + p3);
      u0[n][0] = pkbf(p0, p1);
      u0[n][1] = pkbf(p2, p3);
      float r0 = __builtin_amdgcn_exp2f(a2[0]);
      float r1 = __builtin_amdgcn_exp2f(a2[1]);
      float r2 = __builtin_amdgcn_exp2f(a2[2]);
      float r3 = __builtin_amdgcn_exp2f(a2[3]);
      st1 += (r0 + r1) + (r2 + r3);
      u1[n][0] = pkbf(r0, r1);
      u1[n][1] = pkbf(r2, r3);
    }
    __builtin_amdgcn_s_setprio(0);
    lsum0 += st0;
    lsum1 += st1;

    // register exchange: (b4,b5,n0,n1) -> (b5,n0,b4,n1)
#pragma unroll
    for (int c = 0; c < 2; ++c) {
      swap32(u0[0][c], u0[1][c]); swap32(u0[2][c], u0[3][c]);
      swap32(u1[0][c], u1[1][c]); swap32(u1[2][c], u1[3][c]);
    }
#pragma unroll
    for (int c = 0; c < 2; ++c) {
      swap16(u0[0][c], u0[1][c]); swap16(u0[2][c], u0[3][c]);
      swap16(u1[0][c], u1[1][c]); swap16(u1[2][c], u1[3][c]);
    }

    __builtin_amdgcn_s_setprio(1);
#pragma unroll
    for (int ks = 0; ks < 2; ++ks) {
      union { u32 w4[4]; bf16x8 v; } f0, f1;
      f0.w4[0] = u0[2 * ks][0]; f0.w4[1] = u0[2 * ks][1];
      f0.w4[2] = u0[2 * ks + 1][0]; f0.w4[3] = u0[2 * ks + 1][1];
      f1.w4[0] = u1[2 * ks][0]; f1.w4[1] = u1[2 * ks][1];
      f1.w4[2] = u1[2 * ks + 1][0]; f1.w4[3] = u1[2 * ks + 1][1];
#pragma unroll
      for (int dt = 0; dt < 4; ++dt) {
        const int row = dt * 16 + li;
        const int c = (lg + ks * 4) ^ (li & 7);
        const bf16x8 vf = *(const bf16x8*)&V_[row * 64 + c * 8];
        o[0][dt] = mfma16(vf, f0.v, o[0][dt]);
        o[1][dt] = mfma16(vf, f1.v, o[1][dt]);
      }
    }
    __builtin_amdgcn_s_setprio(0);
  };

  const int t0 = kvh * 16;

  stageK(t0, 0); stageV(t0, 0);
  stageK(t0 + 1, 1); stageV(t0 + 1, 1);
  __syncthreads();

  for (int tt = 0; tt < 16; tt += 2) {
    const int t = t0 + tt;
    if (tt + 2 < 16) { stageK(t + 2, (tt + 2) & 3); stageV(t + 2, (tt + 2) & 3); }
    if (tt + 3 < 16) { stageK(t + 3, (tt + 3) & 3); stageV(t + 3, (tt + 3) & 3); }
    tile_body(lK[tt & 3], lV[tt & 3]);
    tile_body(lK[(tt + 1) & 3], lV[(tt + 1) & 3]);
    __syncthreads();
  }

  lsum0 += __shfl_xor(lsum0, 16, 64);
  lsum0 += __shfl_xor(lsum0, 32, 64);
  lsum1 += __shfl_xor(lsum1, 16, 64);
  lsum1 += __shfl_xor(lsum1, 32, 64);

  u16* Op = Opart + (size_t)kvh * 4096 * 1024;
#pragma unroll
  for (int s = 0; s < 2; ++s) {
    const int qrow = b * N1 + q0 + s * 128 + w * 16 + li;
    const size_t orow = (size_t)qrow * 1024 + h * 64;
#pragma unroll
    for (int dt = 0; dt < 4; ++dt) {
      bf16x4 pk;
#pragma unroll
      for (int r = 0; r < 4; ++r) pk[r] = (__bf16)o[s][dt][r];
      *(bf16x4*)&Op[orow + dt * 16 + lg * 4] = pk;
    }
    if (lg == 0)
      Lpart[(size_t)kvh * 4096 * 16 + (size_t)qrow * 16 + h] = (s == 0 ? lsum0 : lsum1);
  }
}

// ---------------- combine kv-half partials: ao = (O0+O1)/(l0+l1) ----------------
__global__ __launch_bounds__(256) void combine(const u16* __restrict__ Opart,
                                               const float* __restrict__ Lpart,
                                               u16* __restrict__ ao) {
  const int row = blockIdx.x;
  const int tid = threadIdx.x;
  const int h = tid >> 4;
  const float l = Lpart[(size_t)row * 16 + h] + Lpart[4096 * 16 + (size_t)row * 16 + h];
  const float inv = 1.f / l;
  const size_t off = (size_t)row * 1024 + tid * 4;
  const bf16x4 a = *(const bf16x4*)&Opart[off];
  const bf16x4 b = *(const bf16x4*)&Opart[(size_t)4096 * 1024 + off];
  bf16x4 o;
#pragma unroll
  for (int j = 0; j < 4; ++j) o[j] = (__bf16)(((float)a[j] + (float)b[j]) * inv);
  *(bf16x4*)&ao[off] = o;
}

// ---------------- LayerNorm over 1024 cols (bf16 in, f32 out) ----------------
__global__ __launch_bounds__(256) void lnorm(const u16* __restrict__ X,
                                             const float* __restrict__ gamma,
                                             const float* __restrict__ beta,
                                             float* __restrict__ out) {
  const int row = blockIdx.x;
  const int tid = threadIdx.x;
  const bf16x4 xv = ((const bf16x4*)(X + (size_t)row * 1024))[tid];
  float4 v;
  v.x = (float)xv[0]; v.y = (float)xv[1]; v.z = (float)xv[2]; v.w = (float)xv[3];
  float s = v.x + v.y + v.z + v.w;
  float sq = v.x * v.x + v.y * v.y + v.z * v.z + v.w * v.w;
#pragma unroll
  for (int d = 1; d < 64; d <<= 1) {
    s += __shfl_xor(s, d, 64);
    sq += __shfl_xor(sq, d, 64);
  }
  __shared__ float red[8];
  const int w = tid >> 6, l = tid & 63;
  if (l == 0) { red[w] = s; red[4 + w] = sq; }
  __syncthreads();
  s = red[0] + red[1] + red[2] + red[3];
  sq = red[4] + red[5] + red[6] + red[7];
  const float mu = s * (1.f / 1024.f);
  const float var = sq * (1.f / 1024.f) - mu * mu;
  const float rstd = rsqrtf(var + 1e-5f);
  const float4 g = ((const float4*)gamma)[tid];
  const float4 bb = ((const float4*)beta)[tid];
  float4 o;
  o.x = (v.x - mu) * rstd * g.x + bb.x;
  o.y = (v.y - mu) * rstd * g.y + bb.y;
  o.z = (v.z - mu) * rstd * g.z + bb.z;
  o.w = (v.w - mu) * rstd * g.w + bb.w;
  ((float4*)(out + (size_t)row * 1024))[tid] = o;
}

extern "C" void kernel_launch(void* const* d_in, const int* in_sizes, int n_in,
                              void* d_out, int out_size, void* d_ws, size_t ws_size,
                              hipStream_t stream) {
  const float* query = (const float*)d_in[0];
  const float* key_ = (const float*)d_in[1];
  const float* value = (const float*)d_in[2];
  const float* Wq = (const float*)d_in[3];
  const float* bq = (const float*)d_in[4];
  const float* Wk = (const float*)d_in[5];
  const float* bk = (const float*)d_in[6];
  const float* Wv = (const float*)d_in[7];
  const float* bv = (const float*)d_in[8];
  const float* Wo = (const float*)d_in[9];
  const float* bo = (const float*)d_in[10];
  const float* gamma = (const float*)d_in[11];
  const float* beta = (const float*)d_in[12];

  constexpr int B = 2, N1 = 2048, N2 = 2048, E = 1024, QKD = 512;
  constexpr int M = B * N1;  // 4096
  const float QSCALE = 0.125f * 1.4426950408889634f;  // 1/sqrt(64) * log2(e)

  char* p = (char*)d_ws;
  auto alloc = [&](size_t bytes) {
    char* r = p;
    p += (bytes + 255) & ~(size_t)255;
    return r;
  };
  u16* xq = (u16*)alloc((size_t)M * QKD * 2);
  u16* xk = (u16*)alloc((size_t)M * QKD * 2);
  u16* xv = (u16*)alloc((size_t)M * QKD * 2);
  u16* wqt = (u16*)alloc((size_t)E * QKD * 2);
  u16* wkt = (u16*)alloc((size_t)E * QKD * 2);
  u16* wvt = (u16*)alloc((size_t)E * QKD * 2);
  u16* wot = (u16*)alloc((size_t)E * E * 2);
  u16* Qb = (u16*)alloc((size_t)M * E * 2);
  u16* Kb = (u16*)alloc((size_t)M * E * 2);
  u16* Vt = (u16*)alloc((size_t)M * E * 2);
  u16* ao = (u16*)alloc((size_t)M * E * 2);
  u16* ao2 = (u16*)alloc((size_t)M * E * 2);
  u16* Opart = (u16*)alloc((size_t)2 * M * E * 2);
  float* Lpart = (float*)alloc((size_t)2 * M * 16 * 4);

  const int n4 = M * QKD / 4;
  prep<<<dim3((n4 + 255) / 256, 7), 256, 0, stream>>>(
      (const float4*)query, (const float4*)key_, (const float4*)value,
      (bf16x4*)xq, (bf16x4*)xk, (bf16x4*)xv,
      Wq, Wk, Wv, Wo, wqt, wkt, wvt, wot, n4);

  gemm_qkv8<<<dim3(M / 128, E / 128, 3), 512, 0, stream>>>(
      xq, xk, xv, wqt, wkt, wvt, bq, bk, bv, Qb, Kb, Vt, QSCALE);

  attn64<<<dim3(8, 16, 4), 512, 0, stream>>>(Qb, Kb, Vt, Opart, Lpart, N1, N2);

  combine<<<M, 256, 0, stream>>>(Opart, Lpart, ao);

  gemm_o8<<<dim3(M / 128, E / 128), 512, 0, stream>>>(ao, wot, bo, ao2);

  lnorm<<<M, 256, 0, stream>>>(ao2, gamma, beta, (float*)d_out);
}